// Round 4
// baseline (972.173 us; speedup 1.0000x reference)
//
#include <hip/hip_runtime.h>

#define Bn 4
#define Nn 4096
#define En 131072
#define Hn 128
#define Fn 140
#define FPn 160

typedef __bf16 bf16v8 __attribute__((ext_vector_type(8)));
typedef float f32v4 __attribute__((ext_vector_type(4)));
typedef unsigned short u16;
typedef unsigned int u32;

__device__ __forceinline__ u16 f2bf(float f) {
  union { float f; u32 u; } v; v.f = f;
  u32 r = v.u + 0x7fffu + ((v.u >> 16) & 1u);
  return (u16)(r >> 16);
}
__device__ __forceinline__ float bflo(u32 u) { union { u32 u; float f; } v; v.u = u << 16; return v.f; }
__device__ __forceinline__ float bfhi(u32 u) { union { u32 u; float f; } v; v.u = u & 0xffff0000u; return v.f; }

// single-instruction packed f32->bf16 (RTNE), T12 primitive
__device__ __forceinline__ u32 pk2bf(float lo, float hi) {
  u32 r;
  asm("v_cvt_pk_bf16_f32 %0, %1, %2" : "=v"(r) : "v"(lo), "v"(hi));
  return r;
}

__device__ __forceinline__ float sigm(float x) { return 1.0f / (1.0f + __expf(-x)); }
__device__ __forceinline__ float fast_tanh(float x) {
  float e = __expf(2.0f * x);
  return 1.0f - 2.0f / (e + 1.0f);
}

__device__ __forceinline__ void zero8(f32v4* acc) {
  f32v4 z = {0.f, 0.f, 0.f, 0.f};
#pragma unroll
  for (int c = 0; c < 8; ++c) acc[c] = z;
}

// MFMA 16x16x32 bf16: A[m=lane&15][k=quad*8+j], B[k][n=lane&15], C row=quad*4+v col=lane&15
__device__ __forceinline__ void wave_gemm(const u16* Xlds, int ldx,
                                          const u16* __restrict__ Wt, int kpad, int K,
                                          f32v4* acc, int lane) {
  const int m = lane & 15, quad = lane >> 4;
  const u16* xp = Xlds + m * ldx + quad * 8;
  const u16* wp = Wt + m * kpad + quad * 8;
  for (int k0 = 0; k0 < K; k0 += 32) {
    bf16v8 a = *(const bf16v8*)(xp + k0);
#pragma unroll
    for (int c = 0; c < 8; ++c) {
      bf16v8 b = *(const bf16v8*)(wp + c * 16 * kpad + k0);
      acc[c] = __builtin_amdgcn_mfma_f32_16x16x32_bf16(a, b, acc[c], 0, 0, 0);
    }
  }
}

template <int ACT>  // 0=tanh, 1=relu
__device__ __forceinline__ void act_store(const f32v4* acc, const float* __restrict__ bias,
                                          u16* dst, int ldd, int lane) {
  const int m = lane & 15, quad = lane >> 4;
#pragma unroll
  for (int c = 0; c < 8; ++c) {
    const int col = c * 16 + m;
    const float bv = bias[col];
#pragma unroll
    for (int v = 0; v < 4; ++v) {
      float x = acc[c][v] + bv;
      x = (ACT == 0) ? fast_tanh(x) : fmaxf(x, 0.f);
      dst[(quad * 4 + v) * ldd + col] = f2bf(x);
    }
  }
}

// ---------------- prep kernels ----------------

struct WD { const float* src; u16* dst; int K; int Kpad; };
struct WT { WD d[15]; };

__global__ __launch_bounds__(256) void wconv_kernel(WT t) {
  WD w = t.d[blockIdx.x];
  const int total = 128 * w.Kpad;
  for (int i = threadIdx.x; i < total; i += 256) {
    int n = i / w.Kpad, k = i - n * w.Kpad;
    float v = (k < w.K) ? w.src[(size_t)k * 128 + n] : 0.f;
    w.dst[i] = f2bf(v);
  }
}

__global__ __launch_bounds__(256) void conv_kernel(const float* __restrict__ a,
                                                   const float* __restrict__ b,
                                                   u16* __restrict__ ab,
                                                   u16* __restrict__ bb) {
  const int n4 = (Bn * Nn * Hn) / 4;
  int idx = blockIdx.x * 256 + threadIdx.x;
  const float* src; u16* dst;
  if (idx < n4) { src = a; dst = ab; }
  else { idx -= n4; src = b; dst = bb; }
  float4 f = ((const float4*)src)[idx];
  uint2 p;
  p.x = (u32)f2bf(f.x) | ((u32)f2bf(f.y) << 16);
  p.y = (u32)f2bf(f.z) | ((u32)f2bf(f.w) << 16);
  ((uint2*)dst)[idx] = p;
}

// ---------------- counting sort of edges by recv ----------------

__global__ __launch_bounds__(256) void hist_kernel(const int* __restrict__ recv,
                                                   int* __restrict__ hist) {
  int e = blockIdx.x * 256 + threadIdx.x;
  if (e < En) atomicAdd(&hist[recv[e]], 1);
}

__global__ __launch_bounds__(256) void scan_kernel(const int* __restrict__ hist,
                                                   int* __restrict__ offs) {
  __shared__ int part[256];
  const int t = threadIdx.x;
  const int base = t * 16;
  int loc[16];
  int s = 0;
#pragma unroll
  for (int j = 0; j < 16; ++j) { loc[j] = hist[base + j]; s += loc[j]; }
  part[t] = s;
  __syncthreads();
  if (t == 0) {
    int run = 0;
    for (int i = 0; i < 256; ++i) { int v = part[i]; part[i] = run; run += v; }
  }
  __syncthreads();
  int run = part[t];
#pragma unroll
  for (int j = 0; j < 16; ++j) { offs[base + j] = run; run += loc[j]; }
}

__global__ __launch_bounds__(256) void scatter_kernel(const int* __restrict__ recv,
                                                      const int* __restrict__ send,
                                                      int* __restrict__ offs,
                                                      int* __restrict__ perm,
                                                      int* __restrict__ sends,
                                                      int* __restrict__ recvs) {
  int e = blockIdx.x * 256 + threadIdx.x;
  if (e < En) {
    int nd = recv[e];
    int pos = atomicAdd(&offs[nd], 1);
    perm[pos] = e;
    recvs[pos] = nd;
    sends[pos] = send[e];
  }
}

// ---------------- msg: dense MLP over sorted edges + fused segment-sum ----------------
// One wave = 32 sorted edge rows (2 MFMA m-tiles); batched over blockIdx.y.
// All 16 A-fragment gathers prefetched into registers before the MFMA loop (deep MLP).

__global__ __launch_bounds__(256, 3) void msg_kernel(
    const u16* __restrict__ hbf, const int* __restrict__ sends, const int* __restrict__ recvs,
    const u16* __restrict__ w1t, const float* __restrict__ b1,
    const u16* __restrict__ w2t, const float* __restrict__ b2,
    float* __restrict__ hmn) {
  __shared__ __align__(16) u16 sX1[4][32][136];
  __shared__ int sRecv[128];
  const int tid = threadIdx.x, wave = tid >> 6, lane = tid & 63;
  const int m = lane & 15, quad = lane >> 4, q8 = quad * 8;
  const int b = blockIdx.y;
  const int blkbase = blockIdx.x * 128;
  const int base = blkbase + wave * 32;  // sorted slot base of this wave
  const size_t hb = (size_t)b * Nn;
  if (tid < 128) sRecv[tid] = recvs[blkbase + tid];

  const u16* rR0 = hbf + ((hb + recvs[base + m]) << 7);
  const u16* rS0 = hbf + ((hb + sends[base + m]) << 7);
  const u16* rR1 = hbf + ((hb + recvs[base + 16 + m]) << 7);
  const u16* rS1 = hbf + ((hb + sends[base + 16 + m]) << 7);

  // prefetch all 16 A fragments (independent 16B loads)
  bf16v8 ar0[4], as0[4], ar1[4], as1[4];
#pragma unroll
  for (int s = 0; s < 4; ++s) {
    ar0[s] = *(const bf16v8*)(rR0 + s * 32 + q8);
    ar1[s] = *(const bf16v8*)(rR1 + s * 32 + q8);
    as0[s] = *(const bf16v8*)(rS0 + s * 32 + q8);
    as1[s] = *(const bf16v8*)(rS1 + s * 32 + q8);
  }

  f32v4 acc0[8], acc1[8];
  zero8(acc0); zero8(acc1);
#pragma unroll
  for (int s = 0; s < 4; ++s) {  // K cols [0,128) = recv
    const u16* wp = w1t + m * 256 + q8 + s * 32;
#pragma unroll
    for (int c = 0; c < 8; ++c) {
      bf16v8 bb = *(const bf16v8*)(wp + c * 16 * 256);
      acc0[c] = __builtin_amdgcn_mfma_f32_16x16x32_bf16(ar0[s], bb, acc0[c], 0, 0, 0);
      acc1[c] = __builtin_amdgcn_mfma_f32_16x16x32_bf16(ar1[s], bb, acc1[c], 0, 0, 0);
    }
  }
#pragma unroll
  for (int s = 0; s < 4; ++s) {  // K cols [128,256) = send
    const u16* wp = w1t + m * 256 + 128 + q8 + s * 32;
#pragma unroll
    for (int c = 0; c < 8; ++c) {
      bf16v8 bb = *(const bf16v8*)(wp + c * 16 * 256);
      acc0[c] = __builtin_amdgcn_mfma_f32_16x16x32_bf16(as0[s], bb, acc0[c], 0, 0, 0);
      acc1[c] = __builtin_amdgcn_mfma_f32_16x16x32_bf16(as1[s], bb, acc1[c], 0, 0, 0);
    }
  }
#pragma unroll
  for (int c = 0; c < 8; ++c) {
    const int col = c * 16 + m;
    const float bv = b1[col];
#pragma unroll
    for (int v = 0; v < 4; ++v) {
      sX1[wave][quad * 4 + v][col] = f2bf(fast_tanh(acc0[c][v] + bv));
      sX1[wave][16 + quad * 4 + v][col] = f2bf(fast_tanh(acc1[c][v] + bv));
    }
  }
  __syncthreads();
  zero8(acc0); zero8(acc1);
  const u16* xp0 = &sX1[wave][m][q8];
  const u16* xp1 = &sX1[wave][16 + m][q8];
#pragma unroll
  for (int k0 = 0; k0 < 128; k0 += 32) {
    bf16v8 a0 = *(const bf16v8*)(xp0 + k0);
    bf16v8 a1 = *(const bf16v8*)(xp1 + k0);
    const u16* wp = w2t + m * 128 + q8 + k0;
#pragma unroll
    for (int c = 0; c < 8; ++c) {
      bf16v8 bb = *(const bf16v8*)(wp + c * 16 * 128);
      acc0[c] = __builtin_amdgcn_mfma_f32_16x16x32_bf16(a0, bb, acc0[c], 0, 0, 0);
      acc1[c] = __builtin_amdgcn_mfma_f32_16x16x32_bf16(a1, bb, acc1[c], 0, 0, 0);
    }
  }
  __syncthreads();  // sX1 reads complete in all waves before overwrite
#pragma unroll
  for (int c = 0; c < 8; ++c) {
    const int col = c * 16 + m;
    const float bv = b2[col];
#pragma unroll
    for (int v = 0; v < 4; ++v) {
      sX1[wave][quad * 4 + v][col] = f2bf(fast_tanh(acc0[c][v] + bv));
      sX1[wave][16 + quad * 4 + v][col] = f2bf(fast_tanh(acc1[c][v] + bv));
    }
  }
  __syncthreads();
  // block-local segment sum: 2 threads per column, 64 rows each.
  const int col = tid & 127;
  const int r0 = (tid >> 7) * 64;
  float sum = 0.f;
  int cur = sRecv[r0];
  for (int r = r0; r < r0 + 64; ++r) {
    int nd = sRecv[r];
    if (nd != cur) {
      atomicAdd(hmn + ((hb + cur) << 7) + col, sum);
      sum = 0.f;
      cur = nd;
    }
    sum += bflo((u32)sX1[r >> 5][r & 31][col]);
  }
  atomicAdd(hmn + ((hb + cur) << 7) + col, sum);
}

// ---------------- pm: edge_attr relu MLP over sorted edges + fused segment-sum ----------------
// Staging: 2 threads per row, compile-time trip counts (18/17 float4) -> the compiler
// emits the whole load burst before the waits (deep memory pipeline), cvt_pk packing.

__global__ __launch_bounds__(256, 3) void pm_kernel(
    const float* __restrict__ ea, const int* __restrict__ perm, const int* __restrict__ recvs,
    const u16* __restrict__ w1t, const float* __restrict__ b1,
    const u16* __restrict__ w2t, const float* __restrict__ b2,
    float* __restrict__ pmn) {
  __shared__ __align__(16) u16 sEA[4][32][168];  // staged bf16 edge_attr; reused for act/out
  __shared__ int sRecv[128];
  __shared__ int sPerm[128];
  const int tid = threadIdx.x, wave = tid >> 6, lane = tid & 63;
  const int m = lane & 15, quad = lane >> 4, q8 = quad * 8;
  const int b = blockIdx.y;
  const int blkbase = blockIdx.x * 128;
  const size_t hb = (size_t)b * Nn;
  if (tid < 128) {
    sRecv[tid] = recvs[blkbase + tid];
    sPerm[tid] = perm[blkbase + tid];
  }
  __syncthreads();

  // gather: thread pair per row; fixed trip counts so loads fully unroll
  {
    const float* eab = ea + (size_t)b * En * Fn;
    const int r = tid >> 1, p = tid & 1;
    const int e = sPerm[r];
    const float* src = eab + (size_t)e * Fn;
    u16* dst = &sEA[r >> 5][r & 31][0];
    if (p == 0) {
#pragma unroll
      for (int c = 0; c < 18; ++c) {
        float4 f = *(const float4*)(src + c * 4);
        uint2 pk; pk.x = pk2bf(f.x, f.y); pk.y = pk2bf(f.z, f.w);
        *(uint2*)(dst + c * 4) = pk;
      }
    } else {
#pragma unroll
      for (int c = 18; c < 35; ++c) {
        float4 f = *(const float4*)(src + c * 4);
        uint2 pk; pk.x = pk2bf(f.x, f.y); pk.y = pk2bf(f.z, f.w);
        *(uint2*)(dst + c * 4) = pk;
      }
    }
  }
  // zero pad cols [140,160): 128 rows x 5 uint2
  for (int i = tid; i < 128 * 5; i += 256) {
    int r = i / 5;
    int cz = i - r * 5;
    uint2 z; z.x = 0u; z.y = 0u;
    *(uint2*)&sEA[r >> 5][r & 31][140 + cz * 4] = z;
  }
  __syncthreads();
  f32v4 acc0[8], acc1[8];
  zero8(acc0); zero8(acc1);
  const u16* xe0 = &sEA[wave][m][q8];
  const u16* xe1 = &sEA[wave][16 + m][q8];
#pragma unroll
  for (int k0 = 0; k0 < FPn; k0 += 32) {  // 5 steps
    bf16v8 a0 = *(const bf16v8*)(xe0 + k0);
    bf16v8 a1 = *(const bf16v8*)(xe1 + k0);
    const u16* wp = w1t + m * FPn + q8 + k0;
#pragma unroll
    for (int c = 0; c < 8; ++c) {
      bf16v8 bb = *(const bf16v8*)(wp + c * 16 * FPn);
      acc0[c] = __builtin_amdgcn_mfma_f32_16x16x32_bf16(a0, bb, acc0[c], 0, 0, 0);
      acc1[c] = __builtin_amdgcn_mfma_f32_16x16x32_bf16(a1, bb, acc1[c], 0, 0, 0);
    }
  }
  __syncthreads();
#pragma unroll
  for (int c = 0; c < 8; ++c) {
    const int col = c * 16 + m;
    const float bv = b1[col];
#pragma unroll
    for (int v = 0; v < 4; ++v) {
      sEA[wave][quad * 4 + v][col] = f2bf(fmaxf(acc0[c][v] + bv, 0.f));
      sEA[wave][16 + quad * 4 + v][col] = f2bf(fmaxf(acc1[c][v] + bv, 0.f));
    }
  }
  __syncthreads();
  zero8(acc0); zero8(acc1);
#pragma unroll
  for (int k0 = 0; k0 < 128; k0 += 32) {
    bf16v8 a0 = *(const bf16v8*)(xe0 + k0);
    bf16v8 a1 = *(const bf16v8*)(xe1 + k0);
    const u16* wp = w2t + m * 128 + q8 + k0;
#pragma unroll
    for (int c = 0; c < 8; ++c) {
      bf16v8 bb = *(const bf16v8*)(wp + c * 16 * 128);
      acc0[c] = __builtin_amdgcn_mfma_f32_16x16x32_bf16(a0, bb, acc0[c], 0, 0, 0);
      acc1[c] = __builtin_amdgcn_mfma_f32_16x16x32_bf16(a1, bb, acc1[c], 0, 0, 0);
    }
  }
  __syncthreads();
#pragma unroll
  for (int c = 0; c < 8; ++c) {
    const int col = c * 16 + m;
    const float bv = b2[col];
#pragma unroll
    for (int v = 0; v < 4; ++v) {
      sEA[wave][quad * 4 + v][col] = f2bf(fmaxf(acc0[c][v] + bv, 0.f));
      sEA[wave][16 + quad * 4 + v][col] = f2bf(fmaxf(acc1[c][v] + bv, 0.f));
    }
  }
  __syncthreads();
  const int col = tid & 127;
  const int r0 = (tid >> 7) * 64;
  float sum = 0.f;
  int cur = sRecv[r0];
  for (int r = r0; r < r0 + 64; ++r) {
    int nd = sRecv[r];
    if (nd != cur) {
      atomicAdd(pmn + ((hb + cur) << 7) + col, sum);
      sum = 0.f;
      cur = nd;
    }
    sum += bflo((u32)sEA[r >> 5][r & 31][col]);
  }
  atomicAdd(pmn + ((hb + cur) << 7) + col, sum);
}

// ---------------- node kernel: res MLP + GRU + out MLP (means formed here) ----------------

__global__ __launch_bounds__(256) void node_kernel(
    const u16* __restrict__ inbf, const float* __restrict__ hidden,
    const float* __restrict__ hmn, const float* __restrict__ pmn,
    const int* __restrict__ hist,
    const u16* __restrict__ rw1, const float* __restrict__ rb1,
    const u16* __restrict__ rw2, const float* __restrict__ rb2,
    const u16* __restrict__ irw, const float* __restrict__ irb,
    const u16* __restrict__ iiw, const float* __restrict__ iib,
    const u16* __restrict__ inw, const float* __restrict__ inb,
    const u16* __restrict__ hrw, const u16* __restrict__ hiw, const u16* __restrict__ hhw,
    const u16* __restrict__ o1w, const float* __restrict__ o1b,
    const u16* __restrict__ o2w, const float* __restrict__ o2b,
    const u16* __restrict__ o3w, const float* __restrict__ o3b,
    float* __restrict__ pred, float* __restrict__ new_hidden) {
  __shared__ u16 sA[4][16][136], sB[4][16][136], sC[4][16][136];
  const int tid = threadIdx.x, wave = tid >> 6, lane = tid & 63;
  const int row0 = blockIdx.x * 64 + wave * 16;  // row = b*N + n
  const int m = lane & 15, quad = lane >> 4;
  const int half = lane >> 5, c4 = (lane & 31) * 4;
  for (int i = 0; i < 8; ++i) {
    int r = row0 + i * 2 + half;
    *(uint2*)&sA[wave][i * 2 + half][c4] = *(const uint2*)(inbf + ((size_t)r << 7) + c4);
  }
  __syncthreads();
  f32v4 acc[8];
  zero8(acc);
  wave_gemm(&sA[wave][0][0], 136, rw1, 128, 128, acc, lane);
  act_store<1>(acc, rb1, &sB[wave][0][0], 136, lane);
  __syncthreads();
  zero8(acc);
  wave_gemm(&sB[wave][0][0], 136, rw2, 128, 128, acc, lane);
  __syncthreads();
#pragma unroll
  for (int v = 0; v < 4; ++v) {
    int r = row0 + quad * 4 + v;
    const float ic = 1.f / fmaxf((float)hist[r & (Nn - 1)], 1.f);
    const float* ps = pmn + ((size_t)r << 7);
    const float* hs = hmn + ((size_t)r << 7);
#pragma unroll
    for (int c = 0; c < 8; ++c) {
      int col = c * 16 + m;
      float res = fmaxf(acc[c][v] + rb2[col], 0.f);
      sA[wave][quad * 4 + v][col] = f2bf(res + ps[col] * ic);
      sB[wave][quad * 4 + v][col] = f2bf(hs[col] * ic);
    }
  }
  __syncthreads();
  float rg[8][4];
  zero8(acc);
  wave_gemm(&sA[wave][0][0], 136, irw, 128, 128, acc, lane);
  wave_gemm(&sB[wave][0][0], 136, hrw, 128, 128, acc, lane);
#pragma unroll
  for (int c = 0; c < 8; ++c) {
    int col = c * 16 + m;
#pragma unroll
    for (int v = 0; v < 4; ++v) rg[c][v] = sigm(acc[c][v] + irb[col]);
  }
  f32v4 acc2[8];
  zero8(acc);
  wave_gemm(&sA[wave][0][0], 136, inw, 128, 128, acc, lane);
  zero8(acc2);
  wave_gemm(&sB[wave][0][0], 136, hhw, 128, 128, acc2, lane);
#pragma unroll
  for (int c = 0; c < 8; ++c) {
    int col = c * 16 + m;
#pragma unroll
    for (int v = 0; v < 4; ++v)
      rg[c][v] = fast_tanh(acc[c][v] + inb[col] + rg[c][v] * acc2[c][v]);
  }
  zero8(acc);
  wave_gemm(&sA[wave][0][0], 136, iiw, 128, 128, acc, lane);
  wave_gemm(&sB[wave][0][0], 136, hiw, 128, 128, acc, lane);
  __syncthreads();
#pragma unroll
  for (int v = 0; v < 4; ++v) {
    int r = row0 + quad * 4 + v;
    size_t ro = (size_t)r << 7;
#pragma unroll
    for (int c = 0; c < 8; ++c) {
      int col = c * 16 + m;
      float ig = sigm(acc[c][v] + iib[col]);
      float h = hidden[ro + col];
      float nh = (1.f - ig) * rg[c][v] + ig * h;
      new_hidden[ro + col] = nh;
      sC[wave][quad * 4 + v][col] = f2bf(nh);
    }
  }
  __syncthreads();
  zero8(acc);
  wave_gemm(&sC[wave][0][0], 136, o1w, 128, 128, acc, lane);
  act_store<1>(acc, o1b, &sA[wave][0][0], 136, lane);
  __syncthreads();
  zero8(acc);
  wave_gemm(&sA[wave][0][0], 136, o2w, 128, 128, acc, lane);
  act_store<1>(acc, o2b, &sB[wave][0][0], 136, lane);
  __syncthreads();
  zero8(acc);
  wave_gemm(&sB[wave][0][0], 136, o3w, 128, 128, acc, lane);
#pragma unroll
  for (int v = 0; v < 4; ++v) {
    int r = row0 + quad * 4 + v;
    size_t ro = (size_t)r << 7;
#pragma unroll
    for (int c = 0; c < 8; ++c) {
      int col = c * 16 + m;
      pred[ro + col] = acc[c][v] + o3b[col];
    }
  }
}

// ---------------- host ----------------

extern "C" void kernel_launch(void* const* d_in, const int* in_sizes, int n_in,
                              void* d_out, int out_size, void* d_ws, size_t ws_size,
                              hipStream_t stream) {
  const float* inputs = (const float*)d_in[0];
  const float* edge_attr = (const float*)d_in[1];
  const int* send = (const int*)d_in[2];
  const int* recv = (const int*)d_in[3];
  const float* hidden = (const float*)d_in[4];
  const float* msg_b1 = (const float*)d_in[6];
  const float* msg_b2 = (const float*)d_in[8];
  const float* pm_b1 = (const float*)d_in[10];
  const float* pm_b2 = (const float*)d_in[12];
  const float* res_b1 = (const float*)d_in[14];
  const float* res_b2 = (const float*)d_in[16];
  const float* ir_b = (const float*)d_in[18];
  const float* ii_b = (const float*)d_in[20];
  const float* in_b = (const float*)d_in[22];
  const float* out_b1 = (const float*)d_in[27];
  const float* out_b2 = (const float*)d_in[29];
  const float* out_b3 = (const float*)d_in[31];

  char* ws = (char*)d_ws;
  size_t off = 0;
  auto alloc = [&](size_t bytes) {
    char* p = ws + off;
    off += (bytes + 255) & ~(size_t)255;
    return p;
  };
  // zeroed region: hist + fp32 accumulators
  int* hist = (int*)alloc((size_t)Nn * 4);
  float* hmn = (float*)alloc((size_t)Bn * Nn * Hn * 4);  // 8 MB (sums -> means in node)
  float* pmn = (float*)alloc((size_t)Bn * Nn * Hn * 4);  // 8 MB
  size_t zero_bytes = off;
  int* offs = (int*)alloc((size_t)Nn * 4);
  int* perm = (int*)alloc((size_t)En * 4);
  int* sends = (int*)alloc((size_t)En * 4);
  int* recvs = (int*)alloc((size_t)En * 4);
  u16* hbf = (u16*)alloc((size_t)Bn * Nn * Hn * 2);
  u16* ibf = (u16*)alloc((size_t)Bn * Nn * Hn * 2);
  u16* w_msg1 = (u16*)alloc(128 * 256 * 2);
  u16* w_msg2 = (u16*)alloc(128 * 128 * 2);
  u16* w_pm1 = (u16*)alloc(128 * FPn * 2);
  u16* w_pm2 = (u16*)alloc(128 * 128 * 2);
  u16* w_res1 = (u16*)alloc(128 * 128 * 2);
  u16* w_res2 = (u16*)alloc(128 * 128 * 2);
  u16* w_ir = (u16*)alloc(128 * 128 * 2);
  u16* w_ii = (u16*)alloc(128 * 128 * 2);
  u16* w_in = (u16*)alloc(128 * 128 * 2);
  u16* w_hr = (u16*)alloc(128 * 128 * 2);
  u16* w_hi = (u16*)alloc(128 * 128 * 2);
  u16* w_hh = (u16*)alloc(128 * 128 * 2);
  u16* w_o1 = (u16*)alloc(128 * 128 * 2);
  u16* w_o2 = (u16*)alloc(128 * 128 * 2);
  u16* w_o3 = (u16*)alloc(128 * 128 * 2);

  hipMemsetAsync(d_ws, 0, zero_bytes, stream);

  WT wt;
  wt.d[0] = WD{(const float*)d_in[5], w_msg1, 256, 256};
  wt.d[1] = WD{(const float*)d_in[7], w_msg2, 128, 128};
  wt.d[2] = WD{(const float*)d_in[9], w_pm1, Fn, FPn};
  wt.d[3] = WD{(const float*)d_in[11], w_pm2, 128, 128};
  wt.d[4] = WD{(const float*)d_in[13], w_res1, 128, 128};
  wt.d[5] = WD{(const float*)d_in[15], w_res2, 128, 128};
  wt.d[6] = WD{(const float*)d_in[17], w_ir, 128, 128};
  wt.d[7] = WD{(const float*)d_in[19], w_ii, 128, 128};
  wt.d[8] = WD{(const float*)d_in[21], w_in, 128, 128};
  wt.d[9] = WD{(const float*)d_in[23], w_hr, 128, 128};
  wt.d[10] = WD{(const float*)d_in[24], w_hi, 128, 128};
  wt.d[11] = WD{(const float*)d_in[26], w_o1, 128, 128};
  wt.d[12] = WD{(const float*)d_in[28], w_o2, 128, 128};
  wt.d[13] = WD{(const float*)d_in[30], w_o3, 128, 128};
  wt.d[14] = WD{(const float*)d_in[25], w_hh, 128, 128};

  wconv_kernel<<<15, 256, 0, stream>>>(wt);
  conv_kernel<<<(2 * Bn * Nn * Hn / 4) / 256, 256, 0, stream>>>(hidden, inputs, hbf, ibf);
  hist_kernel<<<En / 256, 256, 0, stream>>>(recv, hist);
  scan_kernel<<<1, 256, 0, stream>>>(hist, offs);
  scatter_kernel<<<En / 256, 256, 0, stream>>>(recv, send, offs, perm, sends, recvs);

  msg_kernel<<<dim3(En / 128, Bn), 256, 0, stream>>>(hbf, sends, recvs, w_msg1, msg_b1,
                                                     w_msg2, msg_b2, hmn);
  pm_kernel<<<dim3(En / 128, Bn), 256, 0, stream>>>(edge_attr, perm, recvs, w_pm1, pm_b1,
                                                    w_pm2, pm_b2, pmn);

  float* pred = (float*)d_out;
  float* new_hidden = pred + (size_t)Bn * Nn * Hn;
  node_kernel<<<(Bn * Nn) / 64, 256, 0, stream>>>(
      ibf, hidden, hmn, pmn, hist, w_res1, res_b1, w_res2, res_b2, w_ir, ir_b, w_ii, ii_b,
      w_in, in_b, w_hr, w_hi, w_hh, w_o1, out_b1, w_o2, out_b2, w_o3, out_b3, pred,
      new_hidden);
}

// Round 5
// 893.830 us; speedup vs baseline: 1.0876x; 1.0876x over previous
//
#include <hip/hip_runtime.h>

#define Bn 4
#define Nn 4096
#define En 131072
#define Hn 128
#define Fn 140
#define FPn 160

typedef __bf16 bf16v8 __attribute__((ext_vector_type(8)));
typedef float f32v4 __attribute__((ext_vector_type(4)));
typedef unsigned short u16;
typedef unsigned int u32;

__device__ __forceinline__ u16 f2bf(float f) {
  union { float f; u32 u; } v; v.f = f;
  u32 r = v.u + 0x7fffu + ((v.u >> 16) & 1u);
  return (u16)(r >> 16);
}
__device__ __forceinline__ float bflo(u32 u) { union { u32 u; float f; } v; v.u = u << 16; return v.f; }
__device__ __forceinline__ float bfhi(u32 u) { union { u32 u; float f; } v; v.u = u & 0xffff0000u; return v.f; }

// single-instruction packed f32->bf16 (RTNE), T12 primitive
__device__ __forceinline__ u32 pk2bf(float lo, float hi) {
  u32 r;
  asm("v_cvt_pk_bf16_f32 %0, %1, %2" : "=v"(r) : "v"(lo), "v"(hi));
  return r;
}

__device__ __forceinline__ float sigm(float x) { return 1.0f / (1.0f + __expf(-x)); }
__device__ __forceinline__ float fast_tanh(float x) {
  float e = __expf(2.0f * x);
  return 1.0f - 2.0f / (e + 1.0f);
}

__device__ __forceinline__ void zero8(f32v4* acc) {
  f32v4 z = {0.f, 0.f, 0.f, 0.f};
#pragma unroll
  for (int c = 0; c < 8; ++c) acc[c] = z;
}

// MFMA 16x16x32 bf16: A[m=lane&15][k=quad*8+j], B[k][n=lane&15], C row=quad*4+v col=lane&15
__device__ __forceinline__ void wave_gemm(const u16* Xlds, int ldx,
                                          const u16* __restrict__ Wt, int kpad, int K,
                                          f32v4* acc, int lane) {
  const int m = lane & 15, quad = lane >> 4;
  const u16* xp = Xlds + m * ldx + quad * 8;
  const u16* wp = Wt + m * kpad + quad * 8;
  for (int k0 = 0; k0 < K; k0 += 32) {
    bf16v8 a = *(const bf16v8*)(xp + k0);
#pragma unroll
    for (int c = 0; c < 8; ++c) {
      bf16v8 b = *(const bf16v8*)(wp + c * 16 * kpad + k0);
      acc[c] = __builtin_amdgcn_mfma_f32_16x16x32_bf16(a, b, acc[c], 0, 0, 0);
    }
  }
}

template <int ACT>  // 0=tanh, 1=relu
__device__ __forceinline__ void act_store(const f32v4* acc, const float* __restrict__ bias,
                                          u16* dst, int ldd, int lane) {
  const int m = lane & 15, quad = lane >> 4;
#pragma unroll
  for (int c = 0; c < 8; ++c) {
    const int col = c * 16 + m;
    const float bv = bias[col];
#pragma unroll
    for (int v = 0; v < 4; ++v) {
      float x = acc[c][v] + bv;
      x = (ACT == 0) ? fast_tanh(x) : fmaxf(x, 0.f);
      dst[(quad * 4 + v) * ldd + col] = f2bf(x);
    }
  }
}

// ---------------- prep kernels ----------------

struct WD { const float* src; u16* dst; int K; int Kpad; };
struct WT { WD d[15]; };

__global__ __launch_bounds__(256) void wconv_kernel(WT t) {
  WD w = t.d[blockIdx.x];
  const int total = 128 * w.Kpad;
  for (int i = threadIdx.x; i < total; i += 256) {
    int n = i / w.Kpad, k = i - n * w.Kpad;
    float v = (k < w.K) ? w.src[(size_t)k * 128 + n] : 0.f;
    w.dst[i] = f2bf(v);
  }
}

__global__ __launch_bounds__(256) void conv_kernel(const float* __restrict__ a,
                                                   const float* __restrict__ b,
                                                   u16* __restrict__ ab,
                                                   u16* __restrict__ bb) {
  const int n4 = (Bn * Nn * Hn) / 4;
  int idx = blockIdx.x * 256 + threadIdx.x;
  const float* src; u16* dst;
  if (idx < n4) { src = a; dst = ab; }
  else { idx -= n4; src = b; dst = bb; }
  float4 f = ((const float4*)src)[idx];
  uint2 p;
  p.x = (u32)f2bf(f.x) | ((u32)f2bf(f.y) << 16);
  p.y = (u32)f2bf(f.z) | ((u32)f2bf(f.w) << 16);
  ((uint2*)dst)[idx] = p;
}

// ---------------- R/S precompute: R = hbf@w1_top + b1, S = hbf@w1_bot (f32) ----------------
// Factors msg layer-1 through nodes: per-edge L1 pre-act = R[recv] + S[send].

__global__ __launch_bounds__(256) void rs_kernel(
    const u16* __restrict__ hbf, const u16* __restrict__ w1t, const float* __restrict__ b1,
    float* __restrict__ Rf, float* __restrict__ Sf) {
  __shared__ u16 sA[4][16][136];
  const int tid = threadIdx.x, wave = tid >> 6, lane = tid & 63;
  const int row0 = blockIdx.x * 64 + wave * 16;  // row = b*N + n
  const int m = lane & 15, quad = lane >> 4;
  const int half = lane >> 5, c4 = (lane & 31) * 4;
  for (int i = 0; i < 8; ++i) {
    int r = row0 + i * 2 + half;
    *(uint2*)&sA[wave][i * 2 + half][c4] = *(const uint2*)(hbf + ((size_t)r << 7) + c4);
  }
  __syncthreads();
  f32v4 accR[8], accS[8];
  zero8(accR); zero8(accS);
  wave_gemm(&sA[wave][0][0], 136, w1t, 256, 128, accR, lane);        // k in [0,128)  = recv part
  wave_gemm(&sA[wave][0][0], 136, w1t + 128, 256, 128, accS, lane);  // k in [128,256) = send part
#pragma unroll
  for (int v = 0; v < 4; ++v) {
    int r = row0 + quad * 4 + v;
    size_t ro = (size_t)r << 7;
#pragma unroll
    for (int c = 0; c < 8; ++c) {
      int col = c * 16 + m;
      Rf[ro + col] = accR[c][v] + b1[col];
      Sf[ro + col] = accS[c][v];
    }
  }
}

// ---------------- counting sort of edges by recv ----------------

__global__ __launch_bounds__(256) void hist_kernel(const int* __restrict__ recv,
                                                   int* __restrict__ hist) {
  int e = blockIdx.x * 256 + threadIdx.x;
  if (e < En) atomicAdd(&hist[recv[e]], 1);
}

__global__ __launch_bounds__(256) void scan_kernel(const int* __restrict__ hist,
                                                   int* __restrict__ offs) {
  __shared__ int part[256];
  const int t = threadIdx.x;
  const int base = t * 16;
  int loc[16];
  int s = 0;
#pragma unroll
  for (int j = 0; j < 16; ++j) { loc[j] = hist[base + j]; s += loc[j]; }
  part[t] = s;
  __syncthreads();
  if (t == 0) {
    int run = 0;
    for (int i = 0; i < 256; ++i) { int v = part[i]; part[i] = run; run += v; }
  }
  __syncthreads();
  int run = part[t];
#pragma unroll
  for (int j = 0; j < 16; ++j) { offs[base + j] = run; run += loc[j]; }
}

__global__ __launch_bounds__(256) void scatter_kernel(const int* __restrict__ recv,
                                                      const int* __restrict__ send,
                                                      int* __restrict__ offs,
                                                      int* __restrict__ perm,
                                                      int* __restrict__ sends,
                                                      int* __restrict__ recvs) {
  int e = blockIdx.x * 256 + threadIdx.x;
  if (e < En) {
    int nd = recv[e];
    int pos = atomicAdd(&offs[nd], 1);
    perm[pos] = e;
    recvs[pos] = nd;
    sends[pos] = send[e];
  }
}

// ---------------- msg: elementwise L1 (via R/S) + L2 GEMM + fused segment-sum ----------------

__global__ __launch_bounds__(256, 4) void msg_kernel(
    const float* __restrict__ Rf, const float* __restrict__ Sf,
    const int* __restrict__ sends, const int* __restrict__ recvs,
    const u16* __restrict__ w2t, const float* __restrict__ b2,
    float* __restrict__ hmn) {
  __shared__ __align__(16) u16 sX1[4][32][136];
  __shared__ int sRecv[128];
  __shared__ int sSend[128];
  const int tid = threadIdx.x, wave = tid >> 6, lane = tid & 63;
  const int m = lane & 15, quad = lane >> 4, q8 = quad * 8;
  const int b = blockIdx.y;
  const int blkbase = blockIdx.x * 128;
  const size_t hb = (size_t)b * Nn;
  if (tid < 128) {
    sRecv[tid] = recvs[blkbase + tid];
    sSend[tid] = sends[blkbase + tid];
  }
  __syncthreads();

  // L1 elementwise: act1 = tanh(R[recv] + S[send]); 2 threads/row, 32 indep float4 loads
  {
    const int row = tid >> 1, hf = (tid & 1) * 64;
    const float* rp = Rf + ((hb + sRecv[row]) << 7) + hf;
    const float* sp = Sf + ((hb + sSend[row]) << 7) + hf;
    u16* dst = &sX1[row >> 5][row & 31][hf];
#pragma unroll
    for (int c = 0; c < 16; ++c) {
      float4 a = *(const float4*)(rp + c * 4);
      float4 d = *(const float4*)(sp + c * 4);
      float x0 = fast_tanh(a.x + d.x), x1 = fast_tanh(a.y + d.y);
      float x2 = fast_tanh(a.z + d.z), x3 = fast_tanh(a.w + d.w);
      uint2 pk; pk.x = pk2bf(x0, x1); pk.y = pk2bf(x2, x3);
      *(uint2*)(dst + c * 4) = pk;
    }
  }
  __syncthreads();

  // L2 GEMM: 2 m-tiles per wave, K=128
  f32v4 acc0[8], acc1[8];
  zero8(acc0); zero8(acc1);
  const u16* xp0 = &sX1[wave][m][q8];
  const u16* xp1 = &sX1[wave][16 + m][q8];
#pragma unroll
  for (int k0 = 0; k0 < 128; k0 += 32) {
    bf16v8 a0 = *(const bf16v8*)(xp0 + k0);
    bf16v8 a1 = *(const bf16v8*)(xp1 + k0);
    const u16* wp = w2t + m * 128 + q8 + k0;
#pragma unroll
    for (int c = 0; c < 8; ++c) {
      bf16v8 bb = *(const bf16v8*)(wp + c * 16 * 128);
      acc0[c] = __builtin_amdgcn_mfma_f32_16x16x32_bf16(a0, bb, acc0[c], 0, 0, 0);
      acc1[c] = __builtin_amdgcn_mfma_f32_16x16x32_bf16(a1, bb, acc1[c], 0, 0, 0);
    }
  }
  __syncthreads();  // all waves done reading sX1 before overwrite
#pragma unroll
  for (int c = 0; c < 8; ++c) {
    const int col = c * 16 + m;
    const float bv = b2[col];
#pragma unroll
    for (int v = 0; v < 4; ++v) {
      sX1[wave][quad * 4 + v][col] = f2bf(fast_tanh(acc0[c][v] + bv));
      sX1[wave][16 + quad * 4 + v][col] = f2bf(fast_tanh(acc1[c][v] + bv));
    }
  }
  __syncthreads();
  // block-local segment sum: 2 threads per column, 64 rows each (sorted recv ids)
  const int col = tid & 127;
  const int r0 = (tid >> 7) * 64;
  float sum = 0.f;
  int cur = sRecv[r0];
  for (int r = r0; r < r0 + 64; ++r) {
    int nd = sRecv[r];
    if (nd != cur) {
      atomicAdd(hmn + ((hb + cur) << 7) + col, sum);
      sum = 0.f;
      cur = nd;
    }
    sum += bflo((u32)sX1[r >> 5][r & 31][col]);
  }
  atomicAdd(hmn + ((hb + cur) << 7) + col, sum);
}

// ---------------- pm: edge_attr relu MLP over sorted edges + fused segment-sum ----------------

__global__ __launch_bounds__(256, 3) void pm_kernel(
    const float* __restrict__ ea, const int* __restrict__ perm, const int* __restrict__ recvs,
    const u16* __restrict__ w1t, const float* __restrict__ b1,
    const u16* __restrict__ w2t, const float* __restrict__ b2,
    float* __restrict__ pmn) {
  __shared__ __align__(16) u16 sEA[4][32][168];  // staged bf16 edge_attr; reused for act/out
  __shared__ int sRecv[128];
  __shared__ int sPerm[128];
  const int tid = threadIdx.x, wave = tid >> 6, lane = tid & 63;
  const int m = lane & 15, quad = lane >> 4, q8 = quad * 8;
  const int b = blockIdx.y;
  const int blkbase = blockIdx.x * 128;
  const size_t hb = (size_t)b * Nn;
  if (tid < 128) {
    sRecv[tid] = recvs[blkbase + tid];
    sPerm[tid] = perm[blkbase + tid];
  }
  __syncthreads();

  // gather: thread pair per row; fixed trip counts so loads fully unroll
  {
    const float* eab = ea + (size_t)b * En * Fn;
    const int r = tid >> 1, p = tid & 1;
    const int e = sPerm[r];
    const float* src = eab + (size_t)e * Fn;
    u16* dst = &sEA[r >> 5][r & 31][0];
    if (p == 0) {
#pragma unroll
      for (int c = 0; c < 18; ++c) {
        float4 f = *(const float4*)(src + c * 4);
        uint2 pk; pk.x = pk2bf(f.x, f.y); pk.y = pk2bf(f.z, f.w);
        *(uint2*)(dst + c * 4) = pk;
      }
    } else {
#pragma unroll
      for (int c = 18; c < 35; ++c) {
        float4 f = *(const float4*)(src + c * 4);
        uint2 pk; pk.x = pk2bf(f.x, f.y); pk.y = pk2bf(f.z, f.w);
        *(uint2*)(dst + c * 4) = pk;
      }
    }
  }
  // zero pad cols [140,160): 128 rows x 5 uint2
  for (int i = tid; i < 128 * 5; i += 256) {
    int r = i / 5;
    int cz = i - r * 5;
    uint2 z; z.x = 0u; z.y = 0u;
    *(uint2*)&sEA[r >> 5][r & 31][140 + cz * 4] = z;
  }
  __syncthreads();
  f32v4 acc0[8], acc1[8];
  zero8(acc0); zero8(acc1);
  const u16* xe0 = &sEA[wave][m][q8];
  const u16* xe1 = &sEA[wave][16 + m][q8];
#pragma unroll
  for (int k0 = 0; k0 < FPn; k0 += 32) {  // 5 steps
    bf16v8 a0 = *(const bf16v8*)(xe0 + k0);
    bf16v8 a1 = *(const bf16v8*)(xe1 + k0);
    const u16* wp = w1t + m * FPn + q8 + k0;
#pragma unroll
    for (int c = 0; c < 8; ++c) {
      bf16v8 bb = *(const bf16v8*)(wp + c * 16 * FPn);
      acc0[c] = __builtin_amdgcn_mfma_f32_16x16x32_bf16(a0, bb, acc0[c], 0, 0, 0);
      acc1[c] = __builtin_amdgcn_mfma_f32_16x16x32_bf16(a1, bb, acc1[c], 0, 0, 0);
    }
  }
  __syncthreads();
#pragma unroll
  for (int c = 0; c < 8; ++c) {
    const int col = c * 16 + m;
    const float bv = b1[col];
#pragma unroll
    for (int v = 0; v < 4; ++v) {
      sEA[wave][quad * 4 + v][col] = f2bf(fmaxf(acc0[c][v] + bv, 0.f));
      sEA[wave][16 + quad * 4 + v][col] = f2bf(fmaxf(acc1[c][v] + bv, 0.f));
    }
  }
  __syncthreads();
  zero8(acc0); zero8(acc1);
#pragma unroll
  for (int k0 = 0; k0 < 128; k0 += 32) {
    bf16v8 a0 = *(const bf16v8*)(xe0 + k0);
    bf16v8 a1 = *(const bf16v8*)(xe1 + k0);
    const u16* wp = w2t + m * 128 + q8 + k0;
#pragma unroll
    for (int c = 0; c < 8; ++c) {
      bf16v8 bb = *(const bf16v8*)(wp + c * 16 * 128);
      acc0[c] = __builtin_amdgcn_mfma_f32_16x16x32_bf16(a0, bb, acc0[c], 0, 0, 0);
      acc1[c] = __builtin_amdgcn_mfma_f32_16x16x32_bf16(a1, bb, acc1[c], 0, 0, 0);
    }
  }
  __syncthreads();
#pragma unroll
  for (int c = 0; c < 8; ++c) {
    const int col = c * 16 + m;
    const float bv = b2[col];
#pragma unroll
    for (int v = 0; v < 4; ++v) {
      sEA[wave][quad * 4 + v][col] = f2bf(fmaxf(acc0[c][v] + bv, 0.f));
      sEA[wave][16 + quad * 4 + v][col] = f2bf(fmaxf(acc1[c][v] + bv, 0.f));
    }
  }
  __syncthreads();
  const int col = tid & 127;
  const int r0 = (tid >> 7) * 64;
  float sum = 0.f;
  int cur = sRecv[r0];
  for (int r = r0; r < r0 + 64; ++r) {
    int nd = sRecv[r];
    if (nd != cur) {
      atomicAdd(pmn + ((hb + cur) << 7) + col, sum);
      sum = 0.f;
      cur = nd;
    }
    sum += bflo((u32)sEA[r >> 5][r & 31][col]);
  }
  atomicAdd(pmn + ((hb + cur) << 7) + col, sum);
}

// ---------------- node kernel: res MLP + GRU + out MLP (means formed here) ----------------

__global__ __launch_bounds__(256) void node_kernel(
    const u16* __restrict__ inbf, const float* __restrict__ hidden,
    const float* __restrict__ hmn, const float* __restrict__ pmn,
    const int* __restrict__ hist,
    const u16* __restrict__ rw1, const float* __restrict__ rb1,
    const u16* __restrict__ rw2, const float* __restrict__ rb2,
    const u16* __restrict__ irw, const float* __restrict__ irb,
    const u16* __restrict__ iiw, const float* __restrict__ iib,
    const u16* __restrict__ inw, const float* __restrict__ inb,
    const u16* __restrict__ hrw, const u16* __restrict__ hiw, const u16* __restrict__ hhw,
    const u16* __restrict__ o1w, const float* __restrict__ o1b,
    const u16* __restrict__ o2w, const float* __restrict__ o2b,
    const u16* __restrict__ o3w, const float* __restrict__ o3b,
    float* __restrict__ pred, float* __restrict__ new_hidden) {
  __shared__ u16 sA[4][16][136], sB[4][16][136], sC[4][16][136];
  const int tid = threadIdx.x, wave = tid >> 6, lane = tid & 63;
  const int row0 = blockIdx.x * 64 + wave * 16;  // row = b*N + n
  const int m = lane & 15, quad = lane >> 4;
  const int half = lane >> 5, c4 = (lane & 31) * 4;
  for (int i = 0; i < 8; ++i) {
    int r = row0 + i * 2 + half;
    *(uint2*)&sA[wave][i * 2 + half][c4] = *(const uint2*)(inbf + ((size_t)r << 7) + c4);
  }
  __syncthreads();
  f32v4 acc[8];
  zero8(acc);
  wave_gemm(&sA[wave][0][0], 136, rw1, 128, 128, acc, lane);
  act_store<1>(acc, rb1, &sB[wave][0][0], 136, lane);
  __syncthreads();
  zero8(acc);
  wave_gemm(&sB[wave][0][0], 136, rw2, 128, 128, acc, lane);
  __syncthreads();
#pragma unroll
  for (int v = 0; v < 4; ++v) {
    int r = row0 + quad * 4 + v;
    const float ic = 1.f / fmaxf((float)hist[r & (Nn - 1)], 1.f);
    const float* ps = pmn + ((size_t)r << 7);
    const float* hs = hmn + ((size_t)r << 7);
#pragma unroll
    for (int c = 0; c < 8; ++c) {
      int col = c * 16 + m;
      float res = fmaxf(acc[c][v] + rb2[col], 0.f);
      sA[wave][quad * 4 + v][col] = f2bf(res + ps[col] * ic);
      sB[wave][quad * 4 + v][col] = f2bf(hs[col] * ic);
    }
  }
  __syncthreads();
  float rg[8][4];
  zero8(acc);
  wave_gemm(&sA[wave][0][0], 136, irw, 128, 128, acc, lane);
  wave_gemm(&sB[wave][0][0], 136, hrw, 128, 128, acc, lane);
#pragma unroll
  for (int c = 0; c < 8; ++c) {
    int col = c * 16 + m;
#pragma unroll
    for (int v = 0; v < 4; ++v) rg[c][v] = sigm(acc[c][v] + irb[col]);
  }
  f32v4 acc2[8];
  zero8(acc);
  wave_gemm(&sA[wave][0][0], 136, inw, 128, 128, acc, lane);
  zero8(acc2);
  wave_gemm(&sB[wave][0][0], 136, hhw, 128, 128, acc2, lane);
#pragma unroll
  for (int c = 0; c < 8; ++c) {
    int col = c * 16 + m;
#pragma unroll
    for (int v = 0; v < 4; ++v)
      rg[c][v] = fast_tanh(acc[c][v] + inb[col] + rg[c][v] * acc2[c][v]);
  }
  zero8(acc);
  wave_gemm(&sA[wave][0][0], 136, iiw, 128, 128, acc, lane);
  wave_gemm(&sB[wave][0][0], 136, hiw, 128, 128, acc, lane);
  __syncthreads();
#pragma unroll
  for (int v = 0; v < 4; ++v) {
    int r = row0 + quad * 4 + v;
    size_t ro = (size_t)r << 7;
#pragma unroll
    for (int c = 0; c < 8; ++c) {
      int col = c * 16 + m;
      float ig = sigm(acc[c][v] + iib[col]);
      float h = hidden[ro + col];
      float nh = (1.f - ig) * rg[c][v] + ig * h;
      new_hidden[ro + col] = nh;
      sC[wave][quad * 4 + v][col] = f2bf(nh);
    }
  }
  __syncthreads();
  zero8(acc);
  wave_gemm(&sC[wave][0][0], 136, o1w, 128, 128, acc, lane);
  act_store<1>(acc, o1b, &sA[wave][0][0], 136, lane);
  __syncthreads();
  zero8(acc);
  wave_gemm(&sA[wave][0][0], 136, o2w, 128, 128, acc, lane);
  act_store<1>(acc, o2b, &sB[wave][0][0], 136, lane);
  __syncthreads();
  zero8(acc);
  wave_gemm(&sB[wave][0][0], 136, o3w, 128, 128, acc, lane);
#pragma unroll
  for (int v = 0; v < 4; ++v) {
    int r = row0 + quad * 4 + v;
    size_t ro = (size_t)r << 7;
#pragma unroll
    for (int c = 0; c < 8; ++c) {
      int col = c * 16 + m;
      pred[ro + col] = acc[c][v] + o3b[col];
    }
  }
}

// ---------------- host ----------------

extern "C" void kernel_launch(void* const* d_in, const int* in_sizes, int n_in,
                              void* d_out, int out_size, void* d_ws, size_t ws_size,
                              hipStream_t stream) {
  const float* inputs = (const float*)d_in[0];
  const float* edge_attr = (const float*)d_in[1];
  const int* send = (const int*)d_in[2];
  const int* recv = (const int*)d_in[3];
  const float* hidden = (const float*)d_in[4];
  const float* msg_b1 = (const float*)d_in[6];
  const float* msg_b2 = (const float*)d_in[8];
  const float* pm_b1 = (const float*)d_in[10];
  const float* pm_b2 = (const float*)d_in[12];
  const float* res_b1 = (const float*)d_in[14];
  const float* res_b2 = (const float*)d_in[16];
  const float* ir_b = (const float*)d_in[18];
  const float* ii_b = (const float*)d_in[20];
  const float* in_b = (const float*)d_in[22];
  const float* out_b1 = (const float*)d_in[27];
  const float* out_b2 = (const float*)d_in[29];
  const float* out_b3 = (const float*)d_in[31];

  char* ws = (char*)d_ws;
  size_t off = 0;
  auto alloc = [&](size_t bytes) {
    char* p = ws + off;
    off += (bytes + 255) & ~(size_t)255;
    return p;
  };
  // zeroed region: hist + fp32 accumulators
  int* hist = (int*)alloc((size_t)Nn * 4);
  float* hmn = (float*)alloc((size_t)Bn * Nn * Hn * 4);  // 8 MB (sums -> means in node)
  float* pmn = (float*)alloc((size_t)Bn * Nn * Hn * 4);  // 8 MB
  size_t zero_bytes = off;
  int* offs = (int*)alloc((size_t)Nn * 4);
  int* perm = (int*)alloc((size_t)En * 4);
  int* sends = (int*)alloc((size_t)En * 4);
  int* recvs = (int*)alloc((size_t)En * 4);
  float* Rf = (float*)alloc((size_t)Bn * Nn * Hn * 4);  // 8 MB
  float* Sf = (float*)alloc((size_t)Bn * Nn * Hn * 4);  // 8 MB
  u16* hbf = (u16*)alloc((size_t)Bn * Nn * Hn * 2);
  u16* ibf = (u16*)alloc((size_t)Bn * Nn * Hn * 2);
  u16* w_msg1 = (u16*)alloc(128 * 256 * 2);
  u16* w_msg2 = (u16*)alloc(128 * 128 * 2);
  u16* w_pm1 = (u16*)alloc(128 * FPn * 2);
  u16* w_pm2 = (u16*)alloc(128 * 128 * 2);
  u16* w_res1 = (u16*)alloc(128 * 128 * 2);
  u16* w_res2 = (u16*)alloc(128 * 128 * 2);
  u16* w_ir = (u16*)alloc(128 * 128 * 2);
  u16* w_ii = (u16*)alloc(128 * 128 * 2);
  u16* w_in = (u16*)alloc(128 * 128 * 2);
  u16* w_hr = (u16*)alloc(128 * 128 * 2);
  u16* w_hi = (u16*)alloc(128 * 128 * 2);
  u16* w_hh = (u16*)alloc(128 * 128 * 2);
  u16* w_o1 = (u16*)alloc(128 * 128 * 2);
  u16* w_o2 = (u16*)alloc(128 * 128 * 2);
  u16* w_o3 = (u16*)alloc(128 * 128 * 2);

  hipMemsetAsync(d_ws, 0, zero_bytes, stream);

  WT wt;
  wt.d[0] = WD{(const float*)d_in[5], w_msg1, 256, 256};
  wt.d[1] = WD{(const float*)d_in[7], w_msg2, 128, 128};
  wt.d[2] = WD{(const float*)d_in[9], w_pm1, Fn, FPn};
  wt.d[3] = WD{(const float*)d_in[11], w_pm2, 128, 128};
  wt.d[4] = WD{(const float*)d_in[13], w_res1, 128, 128};
  wt.d[5] = WD{(const float*)d_in[15], w_res2, 128, 128};
  wt.d[6] = WD{(const float*)d_in[17], w_ir, 128, 128};
  wt.d[7] = WD{(const float*)d_in[19], w_ii, 128, 128};
  wt.d[8] = WD{(const float*)d_in[21], w_in, 128, 128};
  wt.d[9] = WD{(const float*)d_in[23], w_hr, 128, 128};
  wt.d[10] = WD{(const float*)d_in[24], w_hi, 128, 128};
  wt.d[11] = WD{(const float*)d_in[26], w_o1, 128, 128};
  wt.d[12] = WD{(const float*)d_in[28], w_o2, 128, 128};
  wt.d[13] = WD{(const float*)d_in[30], w_o3, 128, 128};
  wt.d[14] = WD{(const float*)d_in[25], w_hh, 128, 128};

  wconv_kernel<<<15, 256, 0, stream>>>(wt);
  conv_kernel<<<(2 * Bn * Nn * Hn / 4) / 256, 256, 0, stream>>>(hidden, inputs, hbf, ibf);
  rs_kernel<<<(Bn * Nn) / 64, 256, 0, stream>>>(hbf, w_msg1, msg_b1, Rf, Sf);
  hist_kernel<<<En / 256, 256, 0, stream>>>(recv, hist);
  scan_kernel<<<1, 256, 0, stream>>>(hist, offs);
  scatter_kernel<<<En / 256, 256, 0, stream>>>(recv, send, offs, perm, sends, recvs);

  msg_kernel<<<dim3(En / 128, Bn), 256, 0, stream>>>(Rf, Sf, sends, recvs, w_msg2, msg_b2,
                                                     hmn);
  pm_kernel<<<dim3(En / 128, Bn), 256, 0, stream>>>(edge_attr, perm, recvs, w_pm1, pm_b1,
                                                    w_pm2, pm_b2, pmn);

  float* pred = (float*)d_out;
  float* new_hidden = pred + (size_t)Bn * Nn * Hn;
  node_kernel<<<(Bn * Nn) / 64, 256, 0, stream>>>(
      ibf, hidden, hmn, pmn, hist, w_res1, res_b1, w_res2, res_b2, w_ir, ir_b, w_ii, ii_b,
      w_in, in_b, w_hr, w_hi, w_hh, w_o1, out_b1, w_o2, out_b2, w_o3, out_b3, pred,
      new_hidden);
}